// Round 9
// baseline (536.960 us; speedup 1.0000x reference)
//
#include <hip/hip_runtime.h>
#include <hip/hip_bf16.h>
#include <stdint.h>

#define D_HID 256

typedef float v4f __attribute__((ext_vector_type(4)));
typedef short v8s __attribute__((ext_vector_type(8)));

static __device__ __forceinline__ unsigned short f2bf(float f) {
    union { float f; uint32_t u; } a; a.f = f;
    uint32_t u = a.u;
    uint32_t r = (u + 0x7FFFu + ((u >> 16) & 1u)) >> 16;   // round-nearest-even
    return (unsigned short)r;
}
static __device__ __forceinline__ float bf2f(unsigned short u) {
    union { uint32_t u; float f; } a; a.u = ((uint32_t)u) << 16;
    return a.f;
}

// ---------------- degree count ----------------
__global__ void deg_kernel(const int* __restrict__ dst, int* __restrict__ degi, int E) {
    int e = blockIdx.x * blockDim.x + threadIdx.x;
    if (e < E) atomicAdd(&degi[dst[e]], 1);
}

__global__ void dinv_kernel(const int* __restrict__ degi, float* __restrict__ dinv, int N) {
    int n = blockIdx.x * blockDim.x + threadIdx.x;
    if (n < N) dinv[n] = rsqrtf((float)degi[n] + 1.0f);
}

// ---------------- exclusive scan ----------------
__global__ __launch_bounds__(256) void scanA(const int* __restrict__ degi,
                                             int* __restrict__ row_off,
                                             int* __restrict__ partials, int N) {
    __shared__ int sdata[256];
    int tid = threadIdx.x;
    int base = blockIdx.x * 1024 + tid * 4;
    int s[4];
#pragma unroll
    for (int j = 0; j < 4; ++j) s[j] = (base + j < N) ? degi[base + j] : 0;
    int t = s[0] + s[1] + s[2] + s[3];
    sdata[tid] = t;
    __syncthreads();
    for (int ofs = 1; ofs < 256; ofs <<= 1) {
        int v = (tid >= ofs) ? sdata[tid - ofs] : 0;
        __syncthreads();
        sdata[tid] += v;
        __syncthreads();
    }
    int excl = sdata[tid] - t;
    int run = excl;
#pragma unroll
    for (int j = 0; j < 4; ++j) {
        if (base + j < N) row_off[base + j] = run;
        run += s[j];
    }
    if (tid == 255) partials[blockIdx.x] = sdata[255];
}

__global__ __launch_bounds__(128) void scanB(int* __restrict__ partials, int nb) {
    __shared__ int s[128];
    int tid = threadIdx.x;
    int v = (tid < nb) ? partials[tid] : 0;
    s[tid] = v;
    __syncthreads();
    for (int ofs = 1; ofs < 128; ofs <<= 1) {
        int t = (tid >= ofs) ? s[tid - ofs] : 0;
        __syncthreads();
        s[tid] += t;
        __syncthreads();
    }
    if (tid < nb) partials[tid] = s[tid] - v;   // exclusive
}

__global__ __launch_bounds__(256) void scanC(int* __restrict__ row_off,
                                             const int* __restrict__ partials, int N) {
    int add = partials[blockIdx.x];
    int base = blockIdx.x * 1024 + threadIdx.x * 4;
#pragma unroll
    for (int j = 0; j < 4; ++j)
        if (base + j < N) row_off[base + j] += add;
}

// ---------------- CSR fill ----------------
__global__ void fill_kernel(const int* __restrict__ src, const int* __restrict__ dst,
                            const int* __restrict__ row_off, int* __restrict__ cursor,
                            const float* __restrict__ dinv, int2* __restrict__ csr, int E) {
    int e = blockIdx.x * blockDim.x + threadIdx.x;
    if (e >= E) return;
    int s = src[e], t = dst[e];
    int pos = row_off[t] + atomicAdd(&cursor[t], 1);
    csr[pos] = make_int2(s, __float_as_int(dinv[s] * dinv[t]));
}

// ---------------- frag-ready weight pack ----------------
// Wfrag[l][s][nt][lane][j] = bf16( W_l[ k = s*32 + (lane>>4)*8 + j ][ n = nt*16 + (lane&15) ] )
// so a wave's B-fragment (n-tile nt, k-step s) is one contiguous 1 KB block.
__global__ __launch_bounds__(256) void wfrag_build(const float* __restrict__ W0,
                                                   const float* __restrict__ W1,
                                                   const float* __restrict__ W2,
                                                   unsigned short* __restrict__ Wfrag) {
    int idx = blockIdx.x * 256 + threadIdx.x;    // 3*65536 total
    int l = idx >> 16;
    int rem = idx & 65535;
    int s = rem >> 13;
    int nt = (rem >> 9) & 15;
    int lane = (rem >> 3) & 63;
    int j = rem & 7;
    int n = nt * 16 + (lane & 15);
    int k = s * 32 + (lane >> 4) * 8 + j;
    const float* W = (l == 0) ? W0 : (l == 1) ? W1 : W2;
    Wfrag[idx] = f2bf(W[k * 256 + n]);
}

// ---------------- embedding: hb = bf16(x @ W_emb + b_emb)  (K=10) ----------------
__global__ __launch_bounds__(256) void emb_kernel(const float* __restrict__ x,
                                                  const float* __restrict__ W,
                                                  const float* __restrict__ b,
                                                  unsigned short* __restrict__ hb, int N) {
    int wave = threadIdx.x >> 6;
    int lane = threadIdx.x & 63;
    int n = blockIdx.x * 4 + wave;
    if (n >= N) return;
    float xv = (lane < 10) ? x[n * 10 + lane] : 0.f;
    float s0 = b[lane * 4 + 0], s1 = b[lane * 4 + 1], s2 = b[lane * 4 + 2], s3 = b[lane * 4 + 3];
#pragma unroll
    for (int k = 0; k < 10; ++k) {
        float xk = __shfl(xv, k);
        s0 += xk * W[k * D_HID + lane * 4 + 0];
        s1 += xk * W[k * D_HID + lane * 4 + 1];
        s2 += xk * W[k * D_HID + lane * 4 + 2];
        s3 += xk * W[k * D_HID + lane * 4 + 3];
    }
    size_t i4 = (size_t)n * D_HID + lane * 4;
    ushort4 o; o.x = f2bf(s0); o.y = f2bf(s1); o.z = f2bf(s2); o.w = f2bf(s3);
    *(ushort4*)&hb[i4] = o;
}

// ---------------- fused GCN layer: gather (g = A_hat h) -> GEMM gW -> +b, relu, +h ----------------
// Uses (A_hat h) W == A_hat (h W) associativity. Block owns 64 rows.
#define LROWS 64
#define PADC 264    // 256 + 8 elem pad => row stride 528 B (bank-spread for frag reads)
__global__ __launch_bounds__(256) void layer_fused(const int* __restrict__ row_off,
                                                   const int* __restrict__ degi,
                                                   const int2* __restrict__ csr,
                                                   const unsigned short* __restrict__ Wfrag,
                                                   const float* __restrict__ dinv,
                                                   const float* __restrict__ bias,
                                                   const unsigned short* __restrict__ hb_old,
                                                   unsigned short* __restrict__ hb_new,
                                                   float* __restrict__ out,
                                                   int N, int last) {
    __shared__ unsigned short g[LROWS * PADC];   // 33792 B
    int w = threadIdx.x >> 6;
    int lane = threadIdx.x & 63;
    int bm = blockIdx.x * LROWS;

    // ---- phase 1: gather 16 rows per wave into LDS (bf16) ----
    for (int r = 0; r < 16; ++r) {
        int row = w * 16 + r;
        int n = bm + row;
        float4 acc = make_float4(0.f, 0.f, 0.f, 0.f);
        if (n < N) {
            int off = row_off[n];
            int d = degi[n];
            int i = 0;
            for (; i + 2 <= d; i += 2) {
                int2 p0 = csr[off + i];
                int2 p1 = csr[off + i + 1];
                float n0 = __int_as_float(p0.y);
                float n1 = __int_as_float(p1.y);
                ushort4 r0 = *(const ushort4*)&hb_old[(size_t)p0.x * D_HID + lane * 4];
                ushort4 r1 = *(const ushort4*)&hb_old[(size_t)p1.x * D_HID + lane * 4];
                acc.x += bf2f(r0.x) * n0 + bf2f(r1.x) * n1;
                acc.y += bf2f(r0.y) * n0 + bf2f(r1.y) * n1;
                acc.z += bf2f(r0.z) * n0 + bf2f(r1.z) * n1;
                acc.w += bf2f(r0.w) * n0 + bf2f(r1.w) * n1;
            }
            if (i < d) {
                int2 p0 = csr[off + i];
                float n0 = __int_as_float(p0.y);
                ushort4 r0 = *(const ushort4*)&hb_old[(size_t)p0.x * D_HID + lane * 4];
                acc.x += bf2f(r0.x) * n0;
                acc.y += bf2f(r0.y) * n0;
                acc.z += bf2f(r0.z) * n0;
                acc.w += bf2f(r0.w) * n0;
            }
            float di = dinv[n];
            float sl = di * di;
            ushort4 sv = *(const ushort4*)&hb_old[(size_t)n * D_HID + lane * 4];
            acc.x += bf2f(sv.x) * sl;
            acc.y += bf2f(sv.y) * sl;
            acc.z += bf2f(sv.z) * sl;
            acc.w += bf2f(sv.w) * sl;
        }
        ushort4 o;
        o.x = f2bf(acc.x); o.y = f2bf(acc.y); o.z = f2bf(acc.z); o.w = f2bf(acc.w);
        *(ushort4*)&g[row * PADC + lane * 4] = o;
    }
    __syncthreads();

    // ---- phase 2: GEMM g @ W, B-frags streamed from L2 (frag-ready layout), no barriers ----
    v4f acc[4][4] = {};
    const unsigned short* Wb = Wfrag + (size_t)(w * 4) * 512;   // this wave's n-tiles
#pragma unroll
    for (int s = 0; s < 8; ++s) {
        v8s a[4], b[4];
#pragma unroll
        for (int mt = 0; mt < 4; ++mt)
            a[mt] = *(const v8s*)&g[(mt * 16 + (lane & 15)) * PADC + s * 32 + (lane >> 4) * 8];
#pragma unroll
        for (int nt = 0; nt < 4; ++nt)
            b[nt] = *(const v8s*)&Wb[(size_t)s * 8192 + (size_t)nt * 512 + lane * 8];
#pragma unroll
        for (int mt = 0; mt < 4; ++mt)
#pragma unroll
            for (int nt = 0; nt < 4; ++nt)
                acc[mt][nt] = __builtin_amdgcn_mfma_f32_16x16x32_bf16(a[mt], b[nt], acc[mt][nt], 0, 0, 0);
    }

    // ---- epilogue: bias + relu + residual; write bf16 (or fp32 out on last layer) ----
    int cc = lane & 15;            // n within 16-tile
    int cr = (lane >> 4) * 4;      // m group within 16-tile
    float bv[4];
#pragma unroll
    for (int nt = 0; nt < 4; ++nt) bv[nt] = bias[w * 64 + nt * 16 + cc];
#pragma unroll
    for (int mt = 0; mt < 4; ++mt) {
#pragma unroll
        for (int q = 0; q < 4; ++q) {
            int m = bm + mt * 16 + cr + q;
            if (m < N) {
#pragma unroll
                for (int nt = 0; nt < 4; ++nt) {
                    int n = w * 64 + nt * 16 + cc;
                    size_t idx = (size_t)m * D_HID + n;
                    float v = fmaxf(acc[mt][nt][q] + bv[nt], 0.f) + bf2f(hb_old[idx]);
                    if (last) out[idx] = v;
                    else      hb_new[idx] = f2bf(v);
                }
            }
        }
    }
}

extern "C" void kernel_launch(void* const* d_in, const int* in_sizes, int n_in,
                              void* d_out, int out_size, void* d_ws, size_t ws_size,
                              hipStream_t stream) {
    const float* x     = (const float*)d_in[0];
    const int*   edge  = (const int*)d_in[1];
    const float* W_emb = (const float*)d_in[2];
    const float* b_emb = (const float*)d_in[3];
    const float* W[3]  = {(const float*)d_in[4], (const float*)d_in[6], (const float*)d_in[8]};
    const float* B[3]  = {(const float*)d_in[5], (const float*)d_in[7], (const float*)d_in[9]};

    int N = in_sizes[0] / 10;       // 100000
    int E = in_sizes[1] / 2;        // 320000
    size_t NH = (size_t)N * D_HID;

    float* out = (float*)d_out;
    unsigned short* hb0   = (unsigned short*)d_ws;      // NH bf16
    unsigned short* hb1   = hb0 + NH;                   // NH bf16
    unsigned short* Wfrag = hb1 + NH;                   // 3*65536 bf16
    int2*  csr = (int2*)(Wfrag + 3 * 65536);            // E
    int*   degi     = (int*)(csr + E);
    float* dinv     = (float*)(degi + N);
    int*   row_off  = (int*)(dinv + N);
    int*   cursor   = row_off + N;
    int*   partials = cursor + N;

    const int* src = edge;
    const int* dst = edge + E;

    int nb = (N + 1023) / 1024;     // 98

    // ---- CSR build (layer-invariant) ----
    hipMemsetAsync(degi, 0, (size_t)N * sizeof(int), stream);
    deg_kernel<<<(E + 255) / 256, 256, 0, stream>>>(dst, degi, E);
    dinv_kernel<<<(N + 255) / 256, 256, 0, stream>>>(degi, dinv, N);
    scanA<<<nb, 256, 0, stream>>>(degi, row_off, partials, N);
    scanB<<<1, 128, 0, stream>>>(partials, nb);
    scanC<<<nb, 256, 0, stream>>>(row_off, partials, N);
    hipMemsetAsync(cursor, 0, (size_t)N * sizeof(int), stream);
    fill_kernel<<<(E + 255) / 256, 256, 0, stream>>>(src, dst, row_off, cursor, dinv, csr, E);

    // ---- weights -> frag-ready bf16 ----
    wfrag_build<<<3 * 256, 256, 0, stream>>>(W[0], W[1], W[2], Wfrag);

    // ---- embedding ----
    emb_kernel<<<(N + 3) / 4, 256, 0, stream>>>(x, W_emb, b_emb, hb0, N);

    // ---- 3 fused GCN layers (ping-pong hb0/hb1) ----
    int lblocks = (N + LROWS - 1) / LROWS;              // 1563
    layer_fused<<<lblocks, 256, 0, stream>>>(row_off, degi, csr, Wfrag + 0 * 65536,
                                             dinv, B[0], hb0, hb1, out, N, 0);
    layer_fused<<<lblocks, 256, 0, stream>>>(row_off, degi, csr, Wfrag + 1 * 65536,
                                             dinv, B[1], hb1, hb0, out, N, 0);
    layer_fused<<<lblocks, 256, 0, stream>>>(row_off, degi, csr, Wfrag + 2 * 65536,
                                             dinv, B[2], hb0, hb1, out, N, 1);
}

// Round 10
// 462.194 us; speedup vs baseline: 1.1618x; 1.1618x over previous
//
#include <hip/hip_runtime.h>
#include <hip/hip_bf16.h>
#include <stdint.h>

#define D_HID 256

typedef float v4f __attribute__((ext_vector_type(4)));
typedef short v8s __attribute__((ext_vector_type(8)));

static __device__ __forceinline__ unsigned short f2bf(float f) {
    union { float f; uint32_t u; } a; a.f = f;
    uint32_t u = a.u;
    uint32_t r = (u + 0x7FFFu + ((u >> 16) & 1u)) >> 16;   // round-nearest-even
    return (unsigned short)r;
}
static __device__ __forceinline__ float bf2f(unsigned short u) {
    union { uint32_t u; float f; } a; a.u = ((uint32_t)u) << 16;
    return a.f;
}

// ---------------- degree count ----------------
__global__ void deg_kernel(const int* __restrict__ dst, int* __restrict__ degi, int E) {
    int e = blockIdx.x * blockDim.x + threadIdx.x;
    if (e < E) atomicAdd(&degi[dst[e]], 1);
}

// ---------------- scanA: block-local exclusive scan + dinv + cursor-zero ----------------
__global__ __launch_bounds__(256) void scanA(const int* __restrict__ degi,
                                             int* __restrict__ row_loc,
                                             int* __restrict__ partials,
                                             float* __restrict__ dinv,
                                             int* __restrict__ cursor, int N) {
    __shared__ int sdata[256];
    int tid = threadIdx.x;
    int base = blockIdx.x * 1024 + tid * 4;
    int s[4];
#pragma unroll
    for (int j = 0; j < 4; ++j) s[j] = (base + j < N) ? degi[base + j] : 0;
    int t = s[0] + s[1] + s[2] + s[3];
    sdata[tid] = t;
    __syncthreads();
    for (int ofs = 1; ofs < 256; ofs <<= 1) {
        int v = (tid >= ofs) ? sdata[tid - ofs] : 0;
        __syncthreads();
        sdata[tid] += v;
        __syncthreads();
    }
    int run = sdata[tid] - t;
#pragma unroll
    for (int j = 0; j < 4; ++j) {
        if (base + j < N) {
            row_loc[base + j] = run;
            dinv[base + j] = rsqrtf((float)s[j] + 1.0f);
            cursor[base + j] = 0;
        }
        run += s[j];
    }
    if (tid == 255) partials[blockIdx.x] = sdata[255];
}

// parallel exclusive scan of <=128 partials
__global__ __launch_bounds__(128) void scanB(int* __restrict__ partials, int nb) {
    __shared__ int s[128];
    int tid = threadIdx.x;
    int v = (tid < nb) ? partials[tid] : 0;
    s[tid] = v;
    __syncthreads();
    for (int ofs = 1; ofs < 128; ofs <<= 1) {
        int t = (tid >= ofs) ? s[tid - ofs] : 0;
        __syncthreads();
        s[tid] += t;
        __syncthreads();
    }
    if (tid < nb) partials[tid] = s[tid] - v;
}

// ---------------- CSR fill (row_loc + partials folded) ----------------
__global__ void fill_kernel(const int* __restrict__ src, const int* __restrict__ dst,
                            const int* __restrict__ row_loc, const int* __restrict__ partials,
                            int* __restrict__ cursor,
                            const float* __restrict__ dinv, int2* __restrict__ csr, int E) {
    int e = blockIdx.x * blockDim.x + threadIdx.x;
    if (e >= E) return;
    int s = src[e], t = dst[e];
    int pos = row_loc[t] + partials[t >> 10] + atomicAdd(&cursor[t], 1);
    csr[pos] = make_int2(s, __float_as_int(dinv[s] * dinv[t]));
}

// ---------------- frag-ready weight pack ----------------
// Wfrag idx (shorts) = l*65536 + (((s*16 + nt)*64 + lane)*8 + j)
// value = bf16( W_l[ k = s*32 + (lane>>4)*8 + j ][ n = nt*16 + (lane&15) ] )
__global__ __launch_bounds__(256) void wfrag_build(const float* __restrict__ W0,
                                                   const float* __restrict__ W1,
                                                   const float* __restrict__ W2,
                                                   unsigned short* __restrict__ Wfrag) {
    int idx = blockIdx.x * 256 + threadIdx.x;
    int l = idx >> 16;
    int rem = idx & 65535;
    int s = rem >> 13;
    int nt = (rem >> 9) & 15;
    int lane = (rem >> 3) & 63;
    int j = rem & 7;
    int n = nt * 16 + (lane & 15);
    int k = s * 32 + (lane >> 4) * 8 + j;
    const float* W = (l == 0) ? W0 : (l == 1) ? W1 : W2;
    Wfrag[idx] = f2bf(W[k * 256 + n]);
}

// ---------------- embedding: hb = bf16(x @ W_emb + b_emb)  (K=10) ----------------
__global__ __launch_bounds__(256) void emb_kernel(const float* __restrict__ x,
                                                  const float* __restrict__ W,
                                                  const float* __restrict__ b,
                                                  unsigned short* __restrict__ hb, int N) {
    int wave = threadIdx.x >> 6;
    int lane = threadIdx.x & 63;
    int n = blockIdx.x * 4 + wave;
    if (n >= N) return;
    float xv = (lane < 10) ? x[n * 10 + lane] : 0.f;
    float s0 = b[lane * 4 + 0], s1 = b[lane * 4 + 1], s2 = b[lane * 4 + 2], s3 = b[lane * 4 + 3];
#pragma unroll
    for (int k = 0; k < 10; ++k) {
        float xk = __shfl(xv, k);
        s0 += xk * W[k * D_HID + lane * 4 + 0];
        s1 += xk * W[k * D_HID + lane * 4 + 1];
        s2 += xk * W[k * D_HID + lane * 4 + 2];
        s3 += xk * W[k * D_HID + lane * 4 + 3];
    }
    size_t i4 = (size_t)n * D_HID + lane * 4;
    ushort4 o; o.x = f2bf(s0); o.y = f2bf(s1); o.z = f2bf(s2); o.w = f2bf(s3);
    *(ushort4*)&hb[i4] = o;
}

// ---------------- persistent-B streaming GEMM: hwb = hb @ W ----------------
// Block = 4 waves; wave w owns 2 n-tiles (cols colbase..colbase+31), B-frags held in
// registers for the whole kernel. A-frags direct from global (L1-reuse within block).
// No LDS, no barriers. grid = (gx, 2): blockIdx.y selects column half.
#define GT 64
__global__ __launch_bounds__(256) void gemm_pb(const unsigned short* __restrict__ hb,
                                               const unsigned short* __restrict__ Wfrag,
                                               unsigned short* __restrict__ hwb,
                                               int M, int ntiles) {
    int w = threadIdx.x >> 6;
    int lane = threadIdx.x & 63;
    int fr = lane & 15, hi = lane >> 4;
    int ntb = blockIdx.y * 8 + w * 2;          // first of this wave's two 16-col tiles

    const v8s* Wb = (const v8s*)Wfrag;
    v8s b[2][8];
#pragma unroll
    for (int s = 0; s < 8; ++s) {
#pragma unroll
        for (int j = 0; j < 2; ++j)
            b[j][s] = Wb[(s * 16 + ntb + j) * 64 + lane];
    }

    for (int tile = blockIdx.x; tile < ntiles; tile += gridDim.x) {
        int row0 = tile * GT;
        v4f acc[4][2] = {};
#pragma unroll
        for (int s = 0; s < 8; ++s) {
            v8s a[4];
#pragma unroll
            for (int mt = 0; mt < 4; ++mt) {
                int r = row0 + mt * 16 + fr;
                if (r >= M) r = M - 1;
                a[mt] = *(const v8s*)(hb + (size_t)r * 256 + s * 32 + hi * 8);
            }
#pragma unroll
            for (int mt = 0; mt < 4; ++mt) {
                acc[mt][0] = __builtin_amdgcn_mfma_f32_16x16x32_bf16(a[mt], b[0][s], acc[mt][0], 0, 0, 0);
                acc[mt][1] = __builtin_amdgcn_mfma_f32_16x16x32_bf16(a[mt], b[1][s], acc[mt][1], 0, 0, 0);
            }
        }
        int cc = lane & 15, cr = (lane >> 4) * 4;
        int colb = ntb * 16 + cc;
#pragma unroll
        for (int mt = 0; mt < 4; ++mt) {
#pragma unroll
            for (int q = 0; q < 4; ++q) {
                int r = row0 + mt * 16 + cr + q;
                if (r < M) {
                    hwb[(size_t)r * 256 + colb]      = f2bf(acc[mt][0][q]);
                    hwb[(size_t)r * 256 + colb + 16] = f2bf(acc[mt][1][q]);
                }
            }
        }
    }
}

// ---------------- gather-aggregate + combine: 2 nodes per wave ----------------
__global__ __launch_bounds__(256) void agg_combine2(const int* __restrict__ row_loc,
                                                    const int* __restrict__ degi,
                                                    const int* __restrict__ partials,
                                                    const int2* __restrict__ csr,
                                                    const unsigned short* __restrict__ hwb,
                                                    const float* __restrict__ dinv,
                                                    const float* __restrict__ b,
                                                    unsigned short* __restrict__ hb,
                                                    float* __restrict__ out,
                                                    int N, int last) {
    int wave = threadIdx.x >> 6;
    int lane = threadIdx.x & 63;
    int n0 = (blockIdx.x * 4 + wave) * 2;
    if (n0 >= N) return;
    int n1 = n0 + 1;
    bool has1 = (n1 < N);
    int off0 = row_loc[n0] + partials[n0 >> 10];
    int d0 = degi[n0];
    int d1 = has1 ? degi[n1] : 0;
    int off1 = off0 + d0;                     // CSR is globally contiguous
    float4 a0 = make_float4(0.f, 0.f, 0.f, 0.f);
    float4 a1 = make_float4(0.f, 0.f, 0.f, 0.f);
    int mn = d0 < d1 ? d0 : d1;
    int i = 0;
    for (; i < mn; ++i) {                     // interleaved: 2 loads in flight
        int2 p0 = csr[off0 + i];
        int2 p1 = csr[off1 + i];
        float q0 = __int_as_float(p0.y);
        float q1 = __int_as_float(p1.y);
        ushort4 r0 = *(const ushort4*)&hwb[(size_t)p0.x * D_HID + lane * 4];
        ushort4 r1 = *(const ushort4*)&hwb[(size_t)p1.x * D_HID + lane * 4];
        a0.x += bf2f(r0.x) * q0; a1.x += bf2f(r1.x) * q1;
        a0.y += bf2f(r0.y) * q0; a1.y += bf2f(r1.y) * q1;
        a0.z += bf2f(r0.z) * q0; a1.z += bf2f(r1.z) * q1;
        a0.w += bf2f(r0.w) * q0; a1.w += bf2f(r1.w) * q1;
    }
    for (; i < d0; ++i) {
        int2 p0 = csr[off0 + i];
        float q0 = __int_as_float(p0.y);
        ushort4 r0 = *(const ushort4*)&hwb[(size_t)p0.x * D_HID + lane * 4];
        a0.x += bf2f(r0.x) * q0; a0.y += bf2f(r0.y) * q0;
        a0.z += bf2f(r0.z) * q0; a0.w += bf2f(r0.w) * q0;
    }
    for (i = mn; i < d1; ++i) {
        int2 p1 = csr[off1 + i];
        float q1 = __int_as_float(p1.y);
        ushort4 r1 = *(const ushort4*)&hwb[(size_t)p1.x * D_HID + lane * 4];
        a1.x += bf2f(r1.x) * q1; a1.y += bf2f(r1.y) * q1;
        a1.z += bf2f(r1.z) * q1; a1.w += bf2f(r1.w) * q1;
    }

    float4 bb = *(const float4*)&b[lane * 4];
    {   // node n0
        float di = dinv[n0], sl = di * di;
        size_t i4 = (size_t)n0 * D_HID + lane * 4;
        ushort4 wv = *(const ushort4*)&hwb[i4];
        ushort4 hv = *(const ushort4*)&hb[i4];
        float4 r;
        r.x = fmaxf(a0.x + bf2f(wv.x) * sl + bb.x, 0.f) + bf2f(hv.x);
        r.y = fmaxf(a0.y + bf2f(wv.y) * sl + bb.y, 0.f) + bf2f(hv.y);
        r.z = fmaxf(a0.z + bf2f(wv.z) * sl + bb.z, 0.f) + bf2f(hv.z);
        r.w = fmaxf(a0.w + bf2f(wv.w) * sl + bb.w, 0.f) + bf2f(hv.w);
        if (last) { *(float4*)&out[i4] = r; }
        else {
            ushort4 o; o.x = f2bf(r.x); o.y = f2bf(r.y); o.z = f2bf(r.z); o.w = f2bf(r.w);
            *(ushort4*)&hb[i4] = o;
        }
    }
    if (has1) {  // node n1
        float di = dinv[n1], sl = di * di;
        size_t i4 = (size_t)n1 * D_HID + lane * 4;
        ushort4 wv = *(const ushort4*)&hwb[i4];
        ushort4 hv = *(const ushort4*)&hb[i4];
        float4 r;
        r.x = fmaxf(a1.x + bf2f(wv.x) * sl + bb.x, 0.f) + bf2f(hv.x);
        r.y = fmaxf(a1.y + bf2f(wv.y) * sl + bb.y, 0.f) + bf2f(hv.y);
        r.z = fmaxf(a1.z + bf2f(wv.z) * sl + bb.z, 0.f) + bf2f(hv.z);
        r.w = fmaxf(a1.w + bf2f(wv.w) * sl + bb.w, 0.f) + bf2f(hv.w);
        if (last) { *(float4*)&out[i4] = r; }
        else {
            ushort4 o; o.x = f2bf(r.x); o.y = f2bf(r.y); o.z = f2bf(r.z); o.w = f2bf(r.w);
            *(ushort4*)&hb[i4] = o;
        }
    }
}

extern "C" void kernel_launch(void* const* d_in, const int* in_sizes, int n_in,
                              void* d_out, int out_size, void* d_ws, size_t ws_size,
                              hipStream_t stream) {
    const float* x     = (const float*)d_in[0];
    const int*   edge  = (const int*)d_in[1];
    const float* W_emb = (const float*)d_in[2];
    const float* b_emb = (const float*)d_in[3];
    const float* W[3]  = {(const float*)d_in[4], (const float*)d_in[6], (const float*)d_in[8]};
    const float* B[3]  = {(const float*)d_in[5], (const float*)d_in[7], (const float*)d_in[9]};

    int N = in_sizes[0] / 10;       // 100000
    int E = in_sizes[1] / 2;        // 320000
    size_t NH = (size_t)N * D_HID;

    float* out = (float*)d_out;
    unsigned short* hwb   = (unsigned short*)d_ws;      // NH bf16
    unsigned short* hb    = hwb + NH;                   // NH bf16
    unsigned short* Wfrag = hb + NH;                    // 3*65536 bf16
    int2*  csr = (int2*)(Wfrag + 3 * 65536);            // E
    int*   degi     = (int*)(csr + E);
    float* dinv     = (float*)(degi + N);
    int*   row_loc  = (int*)(dinv + N);
    int*   cursor   = row_loc + N;
    int*   partials = cursor + N;

    const int* src = edge;
    const int* dst = edge + E;

    int nb = (N + 1023) / 1024;     // 98

    // ---- CSR build (layer-invariant) ----
    hipMemsetAsync(degi, 0, (size_t)N * sizeof(int), stream);
    deg_kernel<<<(E + 255) / 256, 256, 0, stream>>>(dst, degi, E);
    scanA<<<nb, 256, 0, stream>>>(degi, row_loc, partials, dinv, cursor, N);
    scanB<<<1, 128, 0, stream>>>(partials, nb);
    fill_kernel<<<(E + 255) / 256, 256, 0, stream>>>(src, dst, row_loc, partials, cursor, dinv, csr, E);

    // ---- weights -> frag-ready bf16 ----
    wfrag_build<<<3 * 256, 256, 0, stream>>>(W[0], W[1], W[2], Wfrag);

    // ---- embedding ----
    emb_kernel<<<(N + 3) / 4, 256, 0, stream>>>(x, W_emb, b_emb, hb, N);

    // ---- 3 GCN layers ----
    int ntiles = (N + GT - 1) / GT;             // 1563
    dim3 ggrid(391, 2);                          // ~3 blocks/CU, 4 tiles/block
    int ablocks = ((N + 1) / 2 + 3) / 4;         // 12500
    for (int l = 0; l < 3; ++l) {
        gemm_pb<<<ggrid, 256, 0, stream>>>(hb, Wfrag + (size_t)l * 65536, hwb, N, ntiles);
        agg_combine2<<<ablocks, 256, 0, stream>>>(row_loc, degi, partials, csr, hwb, dinv,
                                                  B[l], hb, out, N, l == 2 ? 1 : 0);
    }
}

// Round 11
// 317.195 us; speedup vs baseline: 1.6928x; 1.4571x over previous
//
#include <hip/hip_runtime.h>
#include <hip/hip_bf16.h>
#include <stdint.h>

#define D_HID 256

typedef float v4f __attribute__((ext_vector_type(4)));
typedef short v8s __attribute__((ext_vector_type(8)));

#define GLOAD_LDS(g, l) __builtin_amdgcn_global_load_lds( \
    (const __attribute__((address_space(1))) unsigned int*)(g), \
    (__attribute__((address_space(3))) unsigned int*)(l), 16, 0, 0)

static __device__ __forceinline__ unsigned short f2bf(float f) {
    union { float f; uint32_t u; } a; a.f = f;
    uint32_t u = a.u;
    uint32_t r = (u + 0x7FFFu + ((u >> 16) & 1u)) >> 16;   // round-nearest-even
    return (unsigned short)r;
}
static __device__ __forceinline__ float bf2f(unsigned short u) {
    union { uint32_t u; float f; } a; a.u = ((uint32_t)u) << 16;
    return a.f;
}

// ---------------- degree count ----------------
__global__ void deg_kernel(const int* __restrict__ dst, int* __restrict__ degi, int E) {
    int e = blockIdx.x * blockDim.x + threadIdx.x;
    if (e < E) atomicAdd(&degi[dst[e]], 1);
}

// ---------------- scanA: block-local exclusive scan + dinv + cursor-zero ----------------
__global__ __launch_bounds__(256) void scanA(const int* __restrict__ degi,
                                             int* __restrict__ row_loc,
                                             int* __restrict__ partials,
                                             float* __restrict__ dinv,
                                             int* __restrict__ cursor, int N) {
    __shared__ int sdata[256];
    int tid = threadIdx.x;
    int base = blockIdx.x * 1024 + tid * 4;
    int s[4];
#pragma unroll
    for (int j = 0; j < 4; ++j) s[j] = (base + j < N) ? degi[base + j] : 0;
    int t = s[0] + s[1] + s[2] + s[3];
    sdata[tid] = t;
    __syncthreads();
    for (int ofs = 1; ofs < 256; ofs <<= 1) {
        int v = (tid >= ofs) ? sdata[tid - ofs] : 0;
        __syncthreads();
        sdata[tid] += v;
        __syncthreads();
    }
    int run = sdata[tid] - t;
#pragma unroll
    for (int j = 0; j < 4; ++j) {
        if (base + j < N) {
            row_loc[base + j] = run;
            dinv[base + j] = rsqrtf((float)s[j] + 1.0f);
            cursor[base + j] = 0;
        }
        run += s[j];
    }
    if (tid == 255) partials[blockIdx.x] = sdata[255];
}

// parallel exclusive scan of <=128 partials
__global__ __launch_bounds__(128) void scanB(int* __restrict__ partials, int nb) {
    __shared__ int s[128];
    int tid = threadIdx.x;
    int v = (tid < nb) ? partials[tid] : 0;
    s[tid] = v;
    __syncthreads();
    for (int ofs = 1; ofs < 128; ofs <<= 1) {
        int t = (tid >= ofs) ? s[tid - ofs] : 0;
        __syncthreads();
        s[tid] += t;
        __syncthreads();
    }
    if (tid < nb) partials[tid] = s[tid] - v;
}

// ---------------- CSR fill ----------------
__global__ void fill_kernel(const int* __restrict__ src, const int* __restrict__ dst,
                            const int* __restrict__ row_loc, const int* __restrict__ partials,
                            int* __restrict__ cursor,
                            const float* __restrict__ dinv, int2* __restrict__ csr, int E) {
    int e = blockIdx.x * blockDim.x + threadIdx.x;
    if (e >= E) return;
    int s = src[e], t = dst[e];
    int pos = row_loc[t] + partials[t >> 10] + atomicAdd(&cursor[t], 1);
    csr[pos] = make_int2(s, __float_as_int(dinv[s] * dinv[t]));
}

// ---------------- weight transpose + bf16 cast for all 3 layers: Wt[l][n][k] ----------------
__global__ __launch_bounds__(256) void transpose_cast3(const float* __restrict__ W0,
                                                       const float* __restrict__ W1,
                                                       const float* __restrict__ W2,
                                                       unsigned short* __restrict__ Wt) {
    __shared__ float t[16][17];
    int l = blockIdx.x >> 8;
    int bi = blockIdx.x & 255;
    const float* W = (l == 0) ? W0 : (l == 1) ? W1 : W2;
    int bx = bi & 15, by = bi >> 4;
    int tx = threadIdx.x & 15, ty = threadIdx.x >> 4;
    t[ty][tx] = W[(by * 16 + ty) * 256 + bx * 16 + tx];
    __syncthreads();
    Wt[(size_t)l * 65536 + (size_t)(bx * 16 + ty) * 256 + by * 16 + tx] = f2bf(t[tx][ty]);
}

// ---------------- embedding: hb = bf16(x @ W_emb + b_emb)  (K=10) ----------------
__global__ __launch_bounds__(256) void emb_kernel(const float* __restrict__ x,
                                                  const float* __restrict__ W,
                                                  const float* __restrict__ b,
                                                  unsigned short* __restrict__ hb, int N) {
    int wave = threadIdx.x >> 6;
    int lane = threadIdx.x & 63;
    int n = blockIdx.x * 4 + wave;
    if (n >= N) return;
    float xv = (lane < 10) ? x[n * 10 + lane] : 0.f;
    float s0 = b[lane * 4 + 0], s1 = b[lane * 4 + 1], s2 = b[lane * 4 + 2], s3 = b[lane * 4 + 3];
#pragma unroll
    for (int k = 0; k < 10; ++k) {
        float xk = __shfl(xv, k);
        s0 += xk * W[k * D_HID + lane * 4 + 0];
        s1 += xk * W[k * D_HID + lane * 4 + 1];
        s2 += xk * W[k * D_HID + lane * 4 + 2];
        s3 += xk * W[k * D_HID + lane * 4 + 3];
    }
    size_t i4 = (size_t)n * D_HID + lane * 4;
    ushort4 o; o.x = f2bf(s0); o.y = f2bf(s1); o.z = f2bf(s2); o.w = f2bf(s3);
    *(ushort4*)&hb[i4] = o;
}

// ---------------- bf16 MFMA GEMM (round-6 verbatim): hwb = hb @ W ----------------
#define GBM 128
__global__ __launch_bounds__(256) void gemm_bf16(const unsigned short* __restrict__ hb,
                                                 const unsigned short* __restrict__ Wt,
                                                 unsigned short* __restrict__ hwb, int M) {
    __shared__ unsigned short lds[2 * 12288];   // 48 KB: per buf [A 128*32][B 256*32]
    int tid = threadIdx.x;
    int w = tid >> 6, lane = tid & 63;
    int bm = blockIdx.x * GBM;
    int wr = w >> 1, wc = w & 1;

    v4f acc[4][8] = {};

    const char* hbB = (const char*)hb;
    const char* WtB = (const char*)Wt;

    auto stage = [&](int buf, int k0) {
        unsigned short* Abase = lds + buf * 12288;
        unsigned short* Bbase = Abase + 4096;
#pragma unroll
        for (int r = 0; r < 2; ++r) {                       // A: 8 KB
            int p = r * 4096 + w * 1024 + lane * 16;
            int row = p >> 6, colb = p & 63;
            const char* g = hbB + ((size_t)(bm + row) << 9) + k0 * 2 + colb;
            GLOAD_LDS(g, Abase + (p >> 1) - lane * 8);
        }
#pragma unroll
        for (int r = 0; r < 4; ++r) {                       // B: 16 KB
            int p = r * 4096 + w * 1024 + lane * 16;
            int row = p >> 6, colb = p & 63;
            const char* g = WtB + (row << 9) + k0 * 2 + colb;
            GLOAD_LDS(g, Bbase + (p >> 1) - lane * 8);
        }
    };

    auto compute = [&](int buf) {
        const unsigned short* Abase = lds + buf * 12288;
        const unsigned short* Bbase = Abase + 4096;
        v8s a[4], b[8];
#pragma unroll
        for (int m = 0; m < 4; ++m) {
            int row = wr * 64 + m * 16 + (lane & 15);
            a[m] = *(const v8s*)(Abase + row * 32 + (lane >> 4) * 8);
        }
#pragma unroll
        for (int n = 0; n < 8; ++n) {
            int row = wc * 128 + n * 16 + (lane & 15);
            b[n] = *(const v8s*)(Bbase + row * 32 + (lane >> 4) * 8);
        }
#pragma unroll
        for (int m = 0; m < 4; ++m)
#pragma unroll
            for (int n = 0; n < 8; ++n)
                acc[m][n] = __builtin_amdgcn_mfma_f32_16x16x32_bf16(a[m], b[n], acc[m][n], 0, 0, 0);
    };

    stage(0, 0);
    __syncthreads();
#pragma unroll
    for (int t = 0; t < 7; ++t) {
        stage((t + 1) & 1, (t + 1) * 32);
        compute(t & 1);
        __syncthreads();
    }
    compute(1);

#pragma unroll
    for (int m = 0; m < 4; ++m) {
        int rbase = bm + wr * 64 + m * 16 + (lane >> 4) * 4;
#pragma unroll
        for (int n = 0; n < 8; ++n) {
            int col = wc * 128 + n * 16 + (lane & 15);
#pragma unroll
            for (int q = 0; q < 4; ++q) {
                int row = rbase + q;
                if (row < M) hwb[(size_t)row * 256 + col] = f2bf(acc[m][n][q]);
            }
        }
    }
}

// ---------------- gather-aggregate + combine: 1 node/wave, 4-deep edge batching ----------------
__global__ __launch_bounds__(256) void agg_combine(const int* __restrict__ row_loc,
                                                   const int* __restrict__ degi,
                                                   const int* __restrict__ partials,
                                                   const int2* __restrict__ csr,
                                                   const unsigned short* __restrict__ hwb,
                                                   const float* __restrict__ dinv,
                                                   const float* __restrict__ b,
                                                   unsigned short* __restrict__ hb,
                                                   float* __restrict__ out,
                                                   int N, int last) {
    int wave = threadIdx.x >> 6;
    int lane = threadIdx.x & 63;
    int n = blockIdx.x * 4 + wave;
    if (n >= N) return;
    int off = row_loc[n] + partials[n >> 10];
    int d = degi[n];
    float4 acc = make_float4(0.f, 0.f, 0.f, 0.f);
    int i = 0;
    for (; i + 4 <= d; i += 4) {            // 4 independent csr + 4 independent row loads
        int2 p0 = csr[off + i];
        int2 p1 = csr[off + i + 1];
        int2 p2 = csr[off + i + 2];
        int2 p3 = csr[off + i + 3];
        float q0 = __int_as_float(p0.y), q1 = __int_as_float(p1.y);
        float q2 = __int_as_float(p2.y), q3 = __int_as_float(p3.y);
        ushort4 r0 = *(const ushort4*)&hwb[(size_t)p0.x * D_HID + lane * 4];
        ushort4 r1 = *(const ushort4*)&hwb[(size_t)p1.x * D_HID + lane * 4];
        ushort4 r2 = *(const ushort4*)&hwb[(size_t)p2.x * D_HID + lane * 4];
        ushort4 r3 = *(const ushort4*)&hwb[(size_t)p3.x * D_HID + lane * 4];
        acc.x += bf2f(r0.x) * q0 + bf2f(r1.x) * q1 + bf2f(r2.x) * q2 + bf2f(r3.x) * q3;
        acc.y += bf2f(r0.y) * q0 + bf2f(r1.y) * q1 + bf2f(r2.y) * q2 + bf2f(r3.y) * q3;
        acc.z += bf2f(r0.z) * q0 + bf2f(r1.z) * q1 + bf2f(r2.z) * q2 + bf2f(r3.z) * q3;
        acc.w += bf2f(r0.w) * q0 + bf2f(r1.w) * q1 + bf2f(r2.w) * q2 + bf2f(r3.w) * q3;
    }
    for (; i + 2 <= d; i += 2) {
        int2 p0 = csr[off + i];
        int2 p1 = csr[off + i + 1];
        float q0 = __int_as_float(p0.y), q1 = __int_as_float(p1.y);
        ushort4 r0 = *(const ushort4*)&hwb[(size_t)p0.x * D_HID + lane * 4];
        ushort4 r1 = *(const ushort4*)&hwb[(size_t)p1.x * D_HID + lane * 4];
        acc.x += bf2f(r0.x) * q0 + bf2f(r1.x) * q1;
        acc.y += bf2f(r0.y) * q0 + bf2f(r1.y) * q1;
        acc.z += bf2f(r0.z) * q0 + bf2f(r1.z) * q1;
        acc.w += bf2f(r0.w) * q0 + bf2f(r1.w) * q1;
    }
    if (i < d) {
        int2 p0 = csr[off + i];
        float q0 = __int_as_float(p0.y);
        ushort4 r0 = *(const ushort4*)&hwb[(size_t)p0.x * D_HID + lane * 4];
        acc.x += bf2f(r0.x) * q0;
        acc.y += bf2f(r0.y) * q0;
        acc.z += bf2f(r0.z) * q0;
        acc.w += bf2f(r0.w) * q0;
    }
    float di = dinv[n];
    float sl = di * di;
    size_t i4 = (size_t)n * D_HID + lane * 4;
    ushort4 wv4 = *(const ushort4*)&hwb[i4];
    ushort4 hv4 = *(const ushort4*)&hb[i4];
    float4 bb = *(const float4*)&b[lane * 4];
    float4 r;
    r.x = fmaxf(acc.x + bf2f(wv4.x) * sl + bb.x, 0.f) + bf2f(hv4.x);
    r.y = fmaxf(acc.y + bf2f(wv4.y) * sl + bb.y, 0.f) + bf2f(hv4.y);
    r.z = fmaxf(acc.z + bf2f(wv4.z) * sl + bb.z, 0.f) + bf2f(hv4.z);
    r.w = fmaxf(acc.w + bf2f(wv4.w) * sl + bb.w, 0.f) + bf2f(hv4.w);
    if (last) {
        *(float4*)&out[i4] = r;
    } else {
        ushort4 o;
        o.x = f2bf(r.x); o.y = f2bf(r.y); o.z = f2bf(r.z); o.w = f2bf(r.w);
        *(ushort4*)&hb[i4] = o;
    }
}

extern "C" void kernel_launch(void* const* d_in, const int* in_sizes, int n_in,
                              void* d_out, int out_size, void* d_ws, size_t ws_size,
                              hipStream_t stream) {
    const float* x     = (const float*)d_in[0];
    const int*   edge  = (const int*)d_in[1];
    const float* W_emb = (const float*)d_in[2];
    const float* b_emb = (const float*)d_in[3];
    const float* W[3]  = {(const float*)d_in[4], (const float*)d_in[6], (const float*)d_in[8]};
    const float* B[3]  = {(const float*)d_in[5], (const float*)d_in[7], (const float*)d_in[9]};

    int N = in_sizes[0] / 10;       // 100000
    int E = in_sizes[1] / 2;        // 320000
    size_t NH = (size_t)N * D_HID;
    int Mpad = ((N + GBM - 1) / GBM) * GBM;     // 100096

    float* out = (float*)d_out;
    unsigned short* hwb = (unsigned short*)d_ws;        // NH bf16
    unsigned short* hb  = hwb + NH;                     // Mpad*256 bf16 (padded for gemm A reads)
    unsigned short* Wt  = hb + (size_t)Mpad * D_HID;    // 3*65536 bf16
    int2*  csr = (int2*)(Wt + 3 * 65536);               // E
    int*   degi     = (int*)(csr + E);
    float* dinv     = (float*)(degi + N);
    int*   row_loc  = (int*)(dinv + N);
    int*   cursor   = row_loc + N;
    int*   partials = cursor + N;

    const int* src = edge;
    const int* dst = edge + E;

    int nb = (N + 1023) / 1024;     // 98

    // ---- CSR build (layer-invariant, fused) ----
    hipMemsetAsync(degi, 0, (size_t)N * sizeof(int), stream);
    deg_kernel<<<(E + 255) / 256, 256, 0, stream>>>(dst, degi, E);
    scanA<<<nb, 256, 0, stream>>>(degi, row_loc, partials, dinv, cursor, N);
    scanB<<<1, 128, 0, stream>>>(partials, nb);
    fill_kernel<<<(E + 255) / 256, 256, 0, stream>>>(src, dst, row_loc, partials, cursor, dinv, csr, E);

    // ---- weights -> bf16 transposed ----
    transpose_cast3<<<3 * 256, 256, 0, stream>>>(W[0], W[1], W[2], Wt);

    // ---- embedding ----
    emb_kernel<<<(N + 3) / 4, 256, 0, stream>>>(x, W_emb, b_emb, hb, N);

    // ---- 3 GCN layers ----
    int gblocks = (N + GBM - 1) / GBM;          // 782
    int ablocks = (N + 3) / 4;                  // 25000
    for (int l = 0; l < 3; ++l) {
        gemm_bf16<<<gblocks, 256, 0, stream>>>(hb, Wt + (size_t)l * 65536, hwb, N);
        agg_combine<<<ablocks, 256, 0, stream>>>(row_loc, degi, partials, csr, hwb, dinv,
                                                 B[l], hb, out, N, l == 2 ? 1 : 0);
    }
}